// Round 6
// baseline (115.028 us; speedup 1.0000x reference)
//
#include <hip/hip_runtime.h>
#include <hip/hip_bf16.h>

// Problem constants
#define B_SZ   16
#define V_IN   1024
#define V_OUT  4096
#define C_IN   128
#define C_OUT  256
#define K_NB   18
#define NNZ    16384
#define K_GEMM (K_NB * C_IN)   // 2304
#define BK     64
#define NKT    (K_GEMM / BK)   // 36

typedef __attribute__((ext_vector_type(8))) short bf16x8;   // 8 bf16 = 4 VGPRs
typedef __attribute__((ext_vector_type(4))) float f32x4;

#define GLOAD16(src, dst) __builtin_amdgcn_global_load_lds( \
    (const __attribute__((address_space(1))) unsigned int*)(src), \
    (__attribute__((address_space(3))) unsigned int*)(dst), 16, 0, 0)

#define MFMA16(a_, b_, c_) __builtin_amdgcn_mfma_f32_16x16x32_bf16((a_), (b_), (c_), 0, 0, 0)

// ---------------- CSR build ----------------
__global__ void hist_kernel(const int* __restrict__ rows, int* counts) {
    int n = blockIdx.x * blockDim.x + threadIdx.x;
    if (n < NNZ) atomicAdd(&counts[rows[n]], 1);
}

// 1024 threads, shfl-based scan of 4096 counts (4 per thread), 1 barrier
__global__ void scan_kernel(const int* __restrict__ counts, int* offsets, int* cursor) {
    __shared__ int wsum[16];
    int t = threadIdx.x;
    int lane = t & 63, wid = t >> 6;
    int base4 = t * 4;
    int c0 = counts[base4], c1 = counts[base4 + 1], c2 = counts[base4 + 2], c3 = counts[base4 + 3];
    int tot = c0 + c1 + c2 + c3;
    int v = tot;
#pragma unroll
    for (int d = 1; d < 64; d <<= 1) {
        int u = __shfl_up(v, d);
        if (lane >= d) v += u;
    }
    if (lane == 63) wsum[wid] = v;
    __syncthreads();
    int wbase = 0;
#pragma unroll
    for (int w = 0; w < 16; ++w) wbase += (w < wid) ? wsum[w] : 0;
    int incl = wbase + v;
    int excl = incl - tot;
    offsets[base4]     = excl;
    offsets[base4 + 1] = excl + c0;
    offsets[base4 + 2] = excl + c0 + c1;
    offsets[base4 + 3] = excl + c0 + c1 + c2;
    cursor[base4]     = excl;
    cursor[base4 + 1] = excl + c0;
    cursor[base4 + 2] = excl + c0 + c1;
    cursor[base4 + 3] = excl + c0 + c1 + c2;
    if (t == 1023) offsets[V_OUT] = incl;
}

__global__ void fill_kernel(const int* __restrict__ rows, int* cursor, int* perm) {
    int n = blockIdx.x * blockDim.x + threadIdx.x;
    if (n < NNZ) {
        int r = rows[n];
        int pos = atomicAdd(&cursor[r], 1);
        perm[pos] = n;
    }
}

// ---------------- pooling: block = out-row, threads = (batch 16) x (c4 32), float4 loads ----------------
__global__ __launch_bounds__(512) void pool_kernel(
    const float* __restrict__ x, const float* __restrict__ vals,
    const int* __restrict__ cols, const int* __restrict__ offsets,
    const int* __restrict__ perm, __hip_bfloat16* __restrict__ pool) {
    int r = blockIdx.x;
    int t = threadIdx.x;
    int b = t >> 5, c4 = t & 31;
    int j0 = offsets[r], j1 = offsets[r + 1];
    const float4* xb = (const float4*)x + (size_t)b * (V_IN * 32);
    float4 acc = {0.f, 0.f, 0.f, 0.f};
    for (int j = j0; j < j1; ++j) {
        int n = perm[j];
        float v = vals[n];
        float4 xv = xb[cols[n] * 32 + c4];
        acc.x += v * xv.x; acc.y += v * xv.y; acc.z += v * xv.z; acc.w += v * xv.w;
    }
    ushort4 o;
    o.x = __builtin_bit_cast(unsigned short, __float2bfloat16(acc.x));
    o.y = __builtin_bit_cast(unsigned short, __float2bfloat16(acc.y));
    o.z = __builtin_bit_cast(unsigned short, __float2bfloat16(acc.z));
    o.w = __builtin_bit_cast(unsigned short, __float2bfloat16(acc.w));
    ((ushort4*)pool)[((size_t)b * V_OUT + r) * 32 + c4] = o;
}

// ---------------- combined weight (pre-swizzled per-K-tile fragment image) + bias ----------------
__global__ void wcomb_kernel(const float* __restrict__ W1, const float* __restrict__ Wd3,
                             const float* __restrict__ W2d3, const float* __restrict__ Wf,
                             const float* __restrict__ b1, const float* __restrict__ bd3,
                             const float* __restrict__ b2d3, const float* __restrict__ bf,
                             __hip_bfloat16* __restrict__ wTs, float* __restrict__ bias) {
    int idx = blockIdx.x * blockDim.x + threadIdx.x;
    if (idx >= NKT * 16384) {
        int c = idx - NKT * 16384;
        if (c < C_OUT) {
            float v = b1[c];
            if (c < 128)      v += bf[c];
            else if (c < 192) v += b2d3[c - 128];
            else              v += bd3[c - 192];
            bias[c] = v;
        }
        return;
    }
    int kt = idx >> 14;
    int c  = (idx >> 3) & 2047;
    int e  = idx & 7;
    int nrow  = c >> 3;
    int kslot = (c & 7) << 4;
    int kb = kslot ^ ((nrow & 7) << 4);
    int r  = kt * 64 + (kb >> 1) + e;    // global k, 0..2303
    int col = nrow;
    float v;
    if (col < 128)      v = Wf[r * 128 + col];
    else if (col < 192) v = (r < 1536) ? W2d3[r * 64 + (col - 128)] : 0.f;
    else                v = (r < 768)  ? Wd3[r * 64 + (col - 192)]  : 0.f;
    if (r < 128) v += W1[r * 256 + col];
    wTs[idx] = __float2bfloat16(v);
}

// ---------------- gathered GEMM: 256x256 tile, 8 waves (128x64 each), A in 3-slot LDS,
// B fragments direct from global (L1-resident per-K-tile image), single barrier per K-tile ----------------
__global__ __launch_bounds__(512, 2) void gemm_kernel(
    const __hip_bfloat16* __restrict__ pool,    // [16][4096][128] bf16
    const __hip_bfloat16* __restrict__ wTs,     // [36][16384] bf16, fragment-image K-tiles
    const float* __restrict__ bias,             // [256]
    const int* __restrict__ spiral,             // [4096][18]
    float* __restrict__ out)                    // [16][4096][256] f32
{
    // LDS: A slots @0,32768,65536 ; spiral cache @98304 (18432B)
    __shared__ __align__(16) char smem[116736];
    int* spl = (int*)(smem + 98304);

    const int tid  = threadIdx.x;
    const int lane = tid & 63;
    const int wid  = tid >> 6;          // 0..7
    const int q    = wid & 3;           // column-group (balanced skip set)
    const int wm   = (wid >> 2) << 7;   // 0 / 128 row band

    const int bid = blockIdx.x;
    const int bm  = ((bid & 7) << 5) + (bid >> 3);   // bijective XCD swizzle (256 = 8*32)
    const int b   = bm >> 4;                          // batch
    const int v0  = (bm & 15) << 8;                   // m-tile origin within batch

    // cache this block's spiral rows in LDS: 256 rows x 18
    for (int i = tid; i < 256 * K_NB; i += 512) spl[i] = spiral[v0 * K_NB + i];
    asm volatile("s_waitcnt vmcnt(0) lgkmcnt(0)" ::: "memory");
    __builtin_amdgcn_s_barrier();

    const char* poolBytes = (const char*)(pool + (size_t)b * V_OUT * C_IN);
    const char* wTsBytes  = (const char*)wTs;
    // inverse-swizzled source column byte (row&7 == (tid>>3)&7 for all 4 chunks)
    const int sb = ((tid & 7) << 4) ^ (((tid >> 3) & 7) << 4);

    auto stageA = [&](int kt, int slot) {          // 4 gload_lds + 4 spl reads
        const int j   = kt >> 1;
        const int c0b = (kt & 1) << 7;
        char* dst = smem + (slot << 15);
#pragma unroll
        for (int ch = 0; ch < 4; ++ch) {
            int row  = (ch << 6) + (tid >> 3);
            int sidx = spl[row * K_NB + j];
            GLOAD16(poolBytes + ((size_t)sidx << 8) + (c0b + sb),
                    dst + (((ch << 9) + tid) << 4));
        }
    };

    // per-lane fragment-read constants
    const int l15   = lane & 15;
    const int swm   = (lane & 7) << 4;          // frag-row&7 == lane&7
    const int klane = (lane >> 4) << 4;         // 0,16,32,48 (byte)
    const int kk0   = klane ^ swm;              // ks=0 column byte
    const int kk1   = (64 + klane) ^ swm;       // ks=1 column byte
    const int aBase = (wm + l15) << 7;          // lane's A row-base byte offset
    // balanced column-tile set: {2q, 2q+1 (full K), 8+q (mid, kt<24), 12+q (short, kt<12)}
    const int bOff0 = (((2 * q)     << 4) + l15) << 7;
    const int bOff1 = (((2 * q + 1) << 4) + l15) << 7;
    const int bOff2 = (((8 + q)     << 4) + l15) << 7;
    const int bOff3 = (((12 + q)    << 4) + l15) << 7;

    f32x4 acc[8][4] = {};

    stageA(0, 0);
    stageA(1, 1);

    int sl = 0;   // LDS slot of tile kt
    for (int kt = 0; kt < NKT; ++kt) {
        if (kt + 1 < NKT) {
            asm volatile("s_waitcnt vmcnt(4)" ::: "memory");   // A(kt) landed; A(kt+1) in flight
        } else {
            asm volatile("s_waitcnt vmcnt(0)" ::: "memory");
        }
        __builtin_amdgcn_s_barrier();
        __builtin_amdgcn_sched_barrier(0);

        const char* As  = smem + (sl << 15);
        const char* wKt = wTsBytes + ((size_t)kt << 15);
        const bool doMid = kt < 24, doShort = kt < 12;

        // B fragments ks=0 (global, L1-hot)
        bf16x8 b00, b01, b02, b03, b10, b11, b12, b13;
        b00 = *(const bf16x8*)(wKt + bOff0 + kk0);
        b01 = *(const bf16x8*)(wKt + bOff1 + kk0);
        if (doMid)   b02 = *(const bf16x8*)(wKt + bOff2 + kk0);
        if (doShort) b03 = *(const bf16x8*)(wKt + bOff3 + kk0);

        // A fragments ks=0 (LDS)
        bf16x8 a[8];
#pragma unroll
        for (int mi = 0; mi < 8; ++mi)
            a[mi] = *(const bf16x8*)(As + aBase + (mi << 11) + kk0);

        // B fragments ks=1 issued early (latency hidden under ks=0 MFMAs)
        b10 = *(const bf16x8*)(wKt + bOff0 + kk1);
        b11 = *(const bf16x8*)(wKt + bOff1 + kk1);
        if (doMid)   b12 = *(const bf16x8*)(wKt + bOff2 + kk1);
        if (doShort) b13 = *(const bf16x8*)(wKt + bOff3 + kk1);

        // stage A(kt+2) LAST so it is the newest vmem (B-reg waits never drain it)
        if (kt + 2 < NKT) {
            int st = sl + 2; if (st >= 3) st -= 3;
            stageA(kt + 2, st);
        }

        __builtin_amdgcn_s_setprio(1);
#pragma unroll
        for (int mi = 0; mi < 8; ++mi) {
            acc[mi][0] = MFMA16(a[mi], b00, acc[mi][0]);
            acc[mi][1] = MFMA16(a[mi], b01, acc[mi][1]);
        }
        if (doMid) {
#pragma unroll
            for (int mi = 0; mi < 8; ++mi) acc[mi][2] = MFMA16(a[mi], b02, acc[mi][2]);
        }
        if (doShort) {
#pragma unroll
            for (int mi = 0; mi < 8; ++mi) acc[mi][3] = MFMA16(a[mi], b03, acc[mi][3]);
        }
        __builtin_amdgcn_s_setprio(0);

        // A fragments ks=1
#pragma unroll
        for (int mi = 0; mi < 8; ++mi)
            a[mi] = *(const bf16x8*)(As + aBase + (mi << 11) + kk1);

        __builtin_amdgcn_s_setprio(1);
#pragma unroll
        for (int mi = 0; mi < 8; ++mi) {
            acc[mi][0] = MFMA16(a[mi], b10, acc[mi][0]);
            acc[mi][1] = MFMA16(a[mi], b11, acc[mi][1]);
        }
        if (doMid) {
#pragma unroll
            for (int mi = 0; mi < 8; ++mi) acc[mi][2] = MFMA16(a[mi], b12, acc[mi][2]);
        }
        if (doShort) {
#pragma unroll
            for (int mi = 0; mi < 8; ++mi) acc[mi][3] = MFMA16(a[mi], b13, acc[mi][3]);
        }
        __builtin_amdgcn_s_setprio(0);

        sl += 1; if (sl >= 3) sl -= 3;
    }

    // epilogue: +bias, relu, store f32
    const int nt[4] = {2 * q, 2 * q + 1, 8 + q, 12 + q};
#pragma unroll
    for (int ni = 0; ni < 4; ++ni) {
        int col = (nt[ni] << 4) + l15;
        float bz = bias[col];
#pragma unroll
        for (int mi = 0; mi < 8; ++mi) {
            int row0 = v0 + wm + mi * 16 + ((lane >> 4) << 2);
#pragma unroll
            for (int r4 = 0; r4 < 4; ++r4) {
                float v = acc[mi][ni][r4] + bz;
                out[((size_t)(b * V_OUT + row0 + r4)) * C_OUT + col] = v > 0.f ? v : 0.f;
            }
        }
    }
}

extern "C" void kernel_launch(void* const* d_in, const int* in_sizes, int n_in,
                              void* d_out, int out_size, void* d_ws, size_t ws_size,
                              hipStream_t stream) {
    const float* x     = (const float*)d_in[0];
    const float* vals  = (const float*)d_in[1];
    const float* W1    = (const float*)d_in[2];
    const float* b1    = (const float*)d_in[3];
    const float* Wd3   = (const float*)d_in[4];
    const float* bd3   = (const float*)d_in[5];
    const float* W2d3  = (const float*)d_in[6];
    const float* b2d3  = (const float*)d_in[7];
    const float* Wf    = (const float*)d_in[8];
    const float* bf    = (const float*)d_in[9];
    const int*   rows  = (const int*)d_in[10];
    const int*   cols  = (const int*)d_in[11];
    const int*   spiral= (const int*)d_in[12];
    float* out = (float*)d_out;

    // workspace layout
    char* ws = (char*)d_ws;
    __hip_bfloat16* pool = (__hip_bfloat16*)ws;                              // 16,777,216 B
    __hip_bfloat16* wTs  = (__hip_bfloat16*)(ws + 16777216);                 //  1,179,648 B
    float* bias          = (float*)(ws + 16777216 + 1179648);                //      1,024 B
    int*   counts        = (int*)(ws + 16777216 + 1179648 + 1024);
    int*   offsets       = counts + V_OUT;          // V_OUT+1 ints
    int*   cursor        = offsets + V_OUT + 4;     // padded
    int*   perm          = cursor + V_OUT;

    hipMemsetAsync(counts, 0, V_OUT * sizeof(int), stream);
    hist_kernel<<<NNZ / 256, 256, 0, stream>>>(rows, counts);
    scan_kernel<<<1, 1024, 0, stream>>>(counts, offsets, cursor);
    fill_kernel<<<NNZ / 256, 256, 0, stream>>>(rows, cursor, perm);
    pool_kernel<<<V_OUT, 512, 0, stream>>>(x, vals, cols, offsets, perm, pool);
    wcomb_kernel<<<(NKT * 16384 + C_OUT + 255) / 256, 256, 0, stream>>>(
        W1, Wd3, W2d3, Wf, b1, bd3, b2d3, bf, wTs, bias);
    gemm_kernel<<<256, 512, 0, stream>>>(pool, wTs, bias, spiral, out);
}